// Round 6
// baseline (156.013 us; speedup 1.0000x reference)
//
#include <hip/hip_runtime.h>

// ---------- types / helpers ----------
typedef __attribute__((ext_vector_type(8))) short short8;          // 8 x bf16 bits - MFMA A/B frag
typedef __attribute__((ext_vector_type(4))) float f32x4;           // MFMA C/D frag
typedef __attribute__((ext_vector_type(8))) unsigned short ushort8;

typedef const unsigned int __attribute__((address_space(1)))* gas1_t;
typedef unsigned int __attribute__((address_space(3)))* las3_t;

__device__ __forceinline__ void gload_lds16(const void* g, void* l) {
  // async global->LDS, 16B per lane. LDS dest must be wave-uniform base + lane*16 (linear).
  __builtin_amdgcn_global_load_lds((gas1_t)g, (las3_t)l, 16, 0, 0);
}

__device__ __forceinline__ unsigned short f2bf(float f) {
  unsigned int u = __float_as_uint(f);
  u += 0x7FFFu + ((u >> 16) & 1u);
  return (unsigned short)(u >> 16);
}
__device__ __forceinline__ float bf2f(unsigned short b) {
  return __uint_as_float(((unsigned int)b) << 16);
}

// ---------- fp32 -> bf16 convert (x) ----------
__global__ __launch_bounds__(256) void conv_f32_bf16(const float* __restrict__ in,
                                                     unsigned short* __restrict__ out, int n8) {
  int i = blockIdx.x * 256 + threadIdx.x;
  if (i >= n8) return;
  const f32x4* p = (const f32x4*)(in + (size_t)i * 8);
  f32x4 a = p[0], b = p[1];
  ushort8 o;
  o[0]=f2bf(a[0]); o[1]=f2bf(a[1]); o[2]=f2bf(a[2]); o[3]=f2bf(a[3]);
  o[4]=f2bf(b[0]); o[5]=f2bf(b[1]); o[6]=f2bf(b[2]); o[7]=f2bf(b[3]);
  *(ushort8*)(out + (size_t)i * 8) = o;
}

// ---------- transpose+convert W (1024x1024 fp32) -> Wt bf16, 3 matrices ----------
__global__ __launch_bounds__(256) void transconv_w(const float* __restrict__ Wq,
                                                   const float* __restrict__ Wk,
                                                   const float* __restrict__ Wv,
                                                   unsigned short* __restrict__ out) {
  __shared__ unsigned short tile[64][66];
  const float* W = (blockIdx.z == 0) ? Wq : ((blockIdx.z == 1) ? Wk : Wv);
  unsigned short* O = out + (size_t)blockIdx.z * 1048576;
  const int bi = blockIdx.x * 64;
  const int bo = blockIdx.y * 64;
#pragma unroll
  for (int p = 0; p < 16; ++p) {
    int idx = p * 256 + threadIdx.x;
    int r = idx >> 6, c = idx & 63;
    tile[r][c] = f2bf(W[(size_t)(bi + r) * 1024 + bo + c]);
  }
  __syncthreads();
#pragma unroll
  for (int p = 0; p < 16; ++p) {
    int idx = p * 256 + threadIdx.x;
    int r = idx >> 6, c = idx & 63;
    O[(size_t)(bo + r) * 1024 + bi + c] = tile[c][r];
  }
}

// ---------- transpose bf16 [R][C] -> [C][R] (for v -> vt) ----------
__global__ __launch_bounds__(256) void trans_bf16(const unsigned short* __restrict__ in,
                                                  unsigned short* __restrict__ out, int R, int C) {
  __shared__ unsigned short tile[64][66];
  const int br = blockIdx.x * 64, bc = blockIdx.y * 64;
#pragma unroll
  for (int p = 0; p < 16; ++p) {
    int idx = p * 256 + threadIdx.x;
    int r = idx >> 6, c = idx & 63;
    tile[r][c] = in[(size_t)(br + r) * C + bc + c];
  }
  __syncthreads();
#pragma unroll
  for (int p = 0; p < 16; ++p) {
    int idx = p * 256 + threadIdx.x;
    int r = idx >> 6, c = idx & 63;
    out[(size_t)(bc + r) * R + br + c] = tile[c][r];
  }
}

// ---------- reduce split-K partials: out[m][d] = (sum_z P[z][m][d]) / rsum[m] ----------
__global__ __launch_bounds__(256) void reduce_pv(const unsigned short* __restrict__ P,
                                                 const float* __restrict__ rsum,
                                                 float* __restrict__ out) {
  int i = blockIdx.x * 256 + threadIdx.x;
  const int m = (i * 8) >> 10;
  const float inv = 1.0f / rsum[m];
  float s[8] = {0.f, 0.f, 0.f, 0.f, 0.f, 0.f, 0.f, 0.f};
#pragma unroll
  for (int z = 0; z < 4; ++z) {
    ushort8 v = *(const ushort8*)(P + (size_t)z * 4194304 + (size_t)i * 8);
#pragma unroll
    for (int j = 0; j < 8; ++j) s[j] += bf2f(v[j]);
  }
  f32x4 o0, o1;
#pragma unroll
  for (int j = 0; j < 4; ++j) { o0[j] = s[j] * inv; o1[j] = s[4 + j] * inv; }
  f32x4* po = (f32x4*)(out + (size_t)i * 8);
  po[0] = o0; po[1] = o1;
}

// ---------- 256x256-tile bf16 GEMM, B^T convention, counted-vmcnt pipeline ----------
// 512 threads = 8 waves (2 Mrows x 4 Ncols), wave tile 128x64, BK=64 (2 k-steps).
// LDS: A/B tiles as 2 halves of [128][64], double-buffered = 128 KiB.
// T2 swizzle (rule 21, both-sides): linear gload_lds dest; SOURCE col-block
// pre-XOR'd with row&7; ds_read applies the same XOR. Kills the 16-way conflict.
// T4 counted waits: invariant 16 loads in flight at loop top; vmcnt(8) retires
// exactly tile t's 8; raw s_barrier (no drain). Drain (vmcnt 0) only at last tile.
// EPI: 0 = +bias -> bf16 (QKV, z = matrix)   1 = exp(s*scale)+rowsum -> bf16 (scores)
//      2 = split-K PV (z = K-slice, koff = z*K): bf16 partial stores
template <int EPI>
__global__ __launch_bounds__(512, 1) void gemm256(
    const unsigned short* __restrict__ A, const unsigned short* __restrict__ B,
    int lda, int ldb, int K, void* __restrict__ C, int ldc,
    size_t strideBz, size_t strideCz,
    const float* __restrict__ bq, const float* __restrict__ bk, const float* __restrict__ bv,
    float scale, float* __restrict__ rsum) {
  __shared__ unsigned short As[2][2][8192];  // [buf][half][128*64]
  __shared__ unsigned short Bs[2][2][8192];
  const int tid = threadIdx.x;
  const int lane = tid & 63;
  const int w = tid >> 6;          // 0..7
  const int wr = w >> 2;           // 0..1  (M half)
  const int wc = w & 3;            // 0..3  (N quarter)
  const int l16 = lane & 15;
  const int q = lane >> 4;         // 0..3

  // bijective XCD swizzle (nwg % 8 == 0 for all our grids)
  const int nwgx = gridDim.x;
  const int nwg = nwgx * gridDim.y;
  const int lin = blockIdx.y * nwgx + blockIdx.x;
  const int swz = (lin & 7) * (nwg >> 3) + (lin >> 3);
  const int m0 = (swz / nwgx) * 256;
  const int n0 = (swz % nwgx) * 256;
  const int z = blockIdx.z;
  const unsigned short* Bz = B + (size_t)z * strideBz;
  const size_t koff = (EPI == 2) ? (size_t)z * K : 0;  // split-K slice offset

  f32x4 acc[8][4];
#pragma unroll
  for (int i = 0; i < 8; ++i)
#pragma unroll
    for (int j = 0; j < 4; ++j) acc[i][j] = f32x4{0.f, 0.f, 0.f, 0.f};

  // staging source pointers, source-side swizzle: granule g=(j*512+tid) of half h
  // holds col-block (g&7)^(row&7) of row g>>3.
  const unsigned short* ap[2][2];
  const unsigned short* bp[2][2];
#pragma unroll
  for (int h = 0; h < 2; ++h)
#pragma unroll
    for (int j = 0; j < 2; ++j) {
      const int g = (j << 9) + tid;
      const int row = g >> 3;
      const int cb = (g & 7) ^ (row & 7);
      ap[h][j] = A + (size_t)(m0 + h * 128 + row) * lda + koff + cb * 8;
      bp[h][j] = Bz + (size_t)(n0 + h * 128 + row) * ldb + koff + cb * 8;
    }

// 8 gload issues per wave per tile (2 halves x 2 chunks x {A,B})
#define STG(buf, k0)                                                          \
  do {                                                                        \
    _Pragma("unroll") for (int _h = 0; _h < 2; ++_h) {                        \
      _Pragma("unroll") for (int _j = 0; _j < 2; ++_j) {                      \
        gload_lds16(ap[_h][_j] + (k0), &As[buf][_h][((_j << 9) + tid) * 8]);  \
        gload_lds16(bp[_h][_j] + (k0), &Bs[buf][_h][((_j << 9) + tid) * 8]);  \
      }                                                                       \
    }                                                                         \
  } while (0)

  const int NT = K / 64;
  STG(0, 0);
  STG(1, 64);   // 16 outstanding per wave

  for (int t = 0; t < NT; ++t) {
    const int cur = t & 1;
    // wait for tile t's 8 loads; keep tile t+1's 8 in flight (counted, no drain)
    if (t + 1 < NT) {
      asm volatile("s_waitcnt vmcnt(8)" ::: "memory");
    } else {
      asm volatile("s_waitcnt vmcnt(0)" ::: "memory");
    }
    __builtin_amdgcn_sched_barrier(0);
    __builtin_amdgcn_s_barrier();          // all waves' shares of tile t landed
    __builtin_amdgcn_sched_barrier(0);

#pragma unroll
    for (int ks = 0; ks < 2; ++ks) {
      const int sw = ((ks << 2) + q) ^ (l16 & 7);  // swizzled 16B-block index
      short8 bfr[4], afr[8];
#pragma unroll
      for (int ni = 0; ni < 4; ++ni) {
        const int r = ((wc & 1) << 6) + ni * 16 + l16;
        bfr[ni] = *(const short8*)(&Bs[cur][wc >> 1][r * 64 + sw * 8]);
      }
#pragma unroll
      for (int mi = 0; mi < 8; ++mi) {
        const int r = mi * 16 + l16;
        afr[mi] = *(const short8*)(&As[cur][wr][r * 64 + sw * 8]);
      }
#pragma unroll
      for (int mi = 0; mi < 8; ++mi)
#pragma unroll
        for (int ni = 0; ni < 4; ++ni)
          acc[mi][ni] = __builtin_amdgcn_mfma_f32_16x16x32_bf16(afr[mi], bfr[ni], acc[mi][ni], 0, 0, 0);
    }

    __builtin_amdgcn_sched_barrier(0);
    __builtin_amdgcn_s_barrier();          // all waves done reading buf[cur]
    __builtin_amdgcn_sched_barrier(0);
    if (t + 2 < NT) STG(cur, (t + 2) * 64);  // overwrite buf[cur] with tile t+2
  }
#undef STG

  // epilogue: C/D layout col = l16, row = q*4 + r (per 16x16 fragment)
  const int row0 = m0 + wr * 128 + q * 4;
  const int col0 = n0 + wc * 64;

  if constexpr (EPI == 0) {
    unsigned short* O = (unsigned short*)C + (size_t)z * strideCz;
    const float* bias = (z == 0) ? bq : ((z == 1) ? bk : bv);
#pragma unroll
    for (int mi = 0; mi < 8; ++mi)
#pragma unroll
      for (int ni = 0; ni < 4; ++ni) {
        const int col = col0 + ni * 16 + l16;
        const int row = row0 + mi * 16;
        float bvv = bias[col];
#pragma unroll
        for (int r = 0; r < 4; ++r)
          O[(size_t)(row + r) * ldc + col] = f2bf(acc[mi][ni][r] + bvv);
      }
  } else if constexpr (EPI == 1) {
    // exp + fused row-sum of the bf16-ROUNDED values (exactly what PV consumes)
    unsigned short* O = (unsigned short*)C;
#pragma unroll
    for (int mi = 0; mi < 8; ++mi) {
      float rs[4] = {0.f, 0.f, 0.f, 0.f};
      const int row = row0 + mi * 16;
#pragma unroll
      for (int ni = 0; ni < 4; ++ni) {
        const int col = col0 + ni * 16 + l16;
#pragma unroll
        for (int r = 0; r < 4; ++r) {
          unsigned short ub = f2bf(__expf(acc[mi][ni][r] * scale));
          O[(size_t)(row + r) * ldc + col] = ub;
          rs[r] += bf2f(ub);
        }
      }
#pragma unroll
      for (int off = 1; off <= 8; off <<= 1) {
#pragma unroll
        for (int r = 0; r < 4; ++r) rs[r] += __shfl_xor(rs[r], off);
      }
      if (l16 == 0) {
#pragma unroll
        for (int r = 0; r < 4; ++r) unsafeAtomicAdd(&rsum[row + r], rs[r]);
      }
    }
  } else {
    // split-K PV: plain bf16 partial stores
    unsigned short* O = (unsigned short*)C + (size_t)z * strideCz;
#pragma unroll
    for (int mi = 0; mi < 8; ++mi)
#pragma unroll
      for (int ni = 0; ni < 4; ++ni) {
        const int col = col0 + ni * 16 + l16;
        const int row = row0 + mi * 16;
#pragma unroll
        for (int r = 0; r < 4; ++r)
          O[(size_t)(row + r) * ldc + col] = f2bf(acc[mi][ni][r]);
      }
  }
}

// ---------- launch ----------
extern "C" void kernel_launch(void* const* d_in, const int* in_sizes, int n_in,
                              void* d_out, int out_size, void* d_ws, size_t ws_size,
                              hipStream_t stream) {
  const float* x  = (const float*)d_in[0];
  const float* Wq = (const float*)d_in[1];
  const float* bq = (const float*)d_in[2];
  const float* Wk = (const float*)d_in[3];
  const float* bk = (const float*)d_in[4];
  const float* Wv = (const float*)d_in[5];
  const float* bv = (const float*)d_in[6];
  float* out = (float*)d_out;
  char* ws = (char*)d_ws;
  const size_t MB = 1024 * 1024;

  // ws layout (78 MB). Phase A: xb 0-8 | wt 8-14 | qkv 14-38 | vt 38-46 | S 46-78
  //                    Phase B (PV): P 0-32 (xb/wt/qb/kb/vb-head dead) | rsum@37 | vt | S
  unsigned short* xb  = (unsigned short*)(ws + 0);
  unsigned short* wt  = (unsigned short*)(ws + 8 * MB);
  unsigned short* qkv = (unsigned short*)(ws + 14 * MB);
  unsigned short* qb  = qkv;
  unsigned short* kb  = qkv + (size_t)4194304;
  unsigned short* vb  = qkv + (size_t)2 * 4194304;
  float*          rsum= (float*)(ws + 37 * MB);
  unsigned short* vt  = (unsigned short*)(ws + 38 * MB);
  unsigned short* S   = (unsigned short*)(ws + 46 * MB);
  unsigned short* P   = (unsigned short*)(ws + 0);

  // 1) convert x to bf16
  conv_f32_bf16<<<2048, 256, 0, stream>>>(x, xb, 524288);
  // 2) transpose+convert the three weight matrices
  transconv_w<<<dim3(16, 16, 3), 256, 0, stream>>>(Wq, Wk, Wv, wt);
  // 3) QKV projection (bias fused, bf16 out)
  gemm256<0><<<dim3(4, 16, 3), 512, 0, stream>>>(
      xb, wt, 1024, 1024, 1024, qkv, 1024,
      (size_t)1048576, (size_t)4194304, bq, bk, bv, 1.0f, nullptr);
  // 4) transpose v -> vt
  trans_bf16<<<dim3(64, 16), 256, 0, stream>>>(vb, vt, 4096, 1024);
  // 4b) zero rsum (vb dead; rsum lives in its tail)
  hipMemsetAsync(rsum, 0, 4096 * sizeof(float), stream);
  // 5) E = exp(q k^T / 32) with fused rsum accumulation
  gemm256<1><<<dim3(16, 16), 512, 0, stream>>>(
      qb, kb, 1024, 1024, 1024, S, 4096,
      (size_t)0, (size_t)0, nullptr, nullptr, nullptr, 0.03125f, rsum);
  // 6) PV split-K x4: P[z] = E[:, z*1024:+1024] @ v[z*1024:+1024, :]
  gemm256<2><<<dim3(4, 16, 4), 512, 0, stream>>>(
      S, vt, 4096, 4096, 1024, P, 1024,
      (size_t)0, (size_t)4194304, nullptr, nullptr, nullptr, 1.0f, nullptr);
  // 7) out = (sum_z P[z]) / rsum
  reduce_pv<<<2048, 256, 0, stream>>>(P, rsum, out);
}

// Round 7
// 148.774 us; speedup vs baseline: 1.0487x; 1.0487x over previous
//
#include <hip/hip_runtime.h>

// ---------- types / helpers ----------
typedef __attribute__((ext_vector_type(8))) short short8;          // 8 x bf16 bits - MFMA A/B frag
typedef __attribute__((ext_vector_type(4))) float f32x4;           // MFMA C/D frag
typedef __attribute__((ext_vector_type(8))) unsigned short ushort8;

typedef const unsigned int __attribute__((address_space(1)))* gas1_t;
typedef unsigned int __attribute__((address_space(3)))* las3_t;

__device__ __forceinline__ void gload_lds16(const void* g, void* l) {
  // async global->LDS, 16B per lane. LDS dest = wave-uniform base + lane*16 (linear).
  __builtin_amdgcn_global_load_lds((gas1_t)g, (las3_t)l, 16, 0, 0);
}

__device__ __forceinline__ unsigned short f2bf(float f) {
  unsigned int u = __float_as_uint(f);
  u += 0x7FFFu + ((u >> 16) & 1u);
  return (unsigned short)(u >> 16);
}
__device__ __forceinline__ float bf2f(unsigned short b) {
  return __uint_as_float(((unsigned int)b) << 16);
}

// ---------- fp32 -> bf16 convert (x) ----------
__global__ __launch_bounds__(256) void conv_f32_bf16(const float* __restrict__ in,
                                                     unsigned short* __restrict__ out, int n8) {
  int i = blockIdx.x * 256 + threadIdx.x;
  if (i >= n8) return;
  const f32x4* p = (const f32x4*)(in + (size_t)i * 8);
  f32x4 a = p[0], b = p[1];
  ushort8 o;
  o[0]=f2bf(a[0]); o[1]=f2bf(a[1]); o[2]=f2bf(a[2]); o[3]=f2bf(a[3]);
  o[4]=f2bf(b[0]); o[5]=f2bf(b[1]); o[6]=f2bf(b[2]); o[7]=f2bf(b[3]);
  *(ushort8*)(out + (size_t)i * 8) = o;
}

// ---------- transpose+convert W (1024x1024 fp32) -> Wt bf16, 3 matrices ----------
__global__ __launch_bounds__(256) void transconv_w(const float* __restrict__ Wq,
                                                   const float* __restrict__ Wk,
                                                   const float* __restrict__ Wv,
                                                   unsigned short* __restrict__ out) {
  __shared__ unsigned short tile[64][66];
  const float* W = (blockIdx.z == 0) ? Wq : ((blockIdx.z == 1) ? Wk : Wv);
  unsigned short* O = out + (size_t)blockIdx.z * 1048576;
  const int bi = blockIdx.x * 64;
  const int bo = blockIdx.y * 64;
#pragma unroll
  for (int p = 0; p < 16; ++p) {
    int idx = p * 256 + threadIdx.x;
    int r = idx >> 6, c = idx & 63;
    tile[r][c] = f2bf(W[(size_t)(bi + r) * 1024 + bo + c]);
  }
  __syncthreads();
#pragma unroll
  for (int p = 0; p < 16; ++p) {
    int idx = p * 256 + threadIdx.x;
    int r = idx >> 6, c = idx & 63;
    O[(size_t)(bo + r) * 1024 + bi + c] = tile[c][r];
  }
}

// ---------- transpose bf16 [R][C] -> [C][R] (for v -> vt) ----------
__global__ __launch_bounds__(256) void trans_bf16(const unsigned short* __restrict__ in,
                                                  unsigned short* __restrict__ out, int R, int C) {
  __shared__ unsigned short tile[64][66];
  const int br = blockIdx.x * 64, bc = blockIdx.y * 64;
#pragma unroll
  for (int p = 0; p < 16; ++p) {
    int idx = p * 256 + threadIdx.x;
    int r = idx >> 6, c = idx & 63;
    tile[r][c] = in[(size_t)(br + r) * C + bc + c];
  }
  __syncthreads();
#pragma unroll
  for (int p = 0; p < 16; ++p) {
    int idx = p * 256 + threadIdx.x;
    int r = idx >> 6, c = idx & 63;
    out[(size_t)(bc + r) * R + br + c] = tile[c][r];
  }
}

// ---------- reduce split-K partials: out[m][d] = (sum_z P[z][m][d]) / rsum[m] ----------
__global__ __launch_bounds__(256) void reduce_pv(const unsigned short* __restrict__ P,
                                                 const float* __restrict__ rsum,
                                                 float* __restrict__ out) {
  int i = blockIdx.x * 256 + threadIdx.x;
  const int m = (i * 8) >> 10;
  const float inv = 1.0f / rsum[m];
  float s[8] = {0.f, 0.f, 0.f, 0.f, 0.f, 0.f, 0.f, 0.f};
#pragma unroll
  for (int z = 0; z < 4; ++z) {
    ushort8 v = *(const ushort8*)(P + (size_t)z * 4194304 + (size_t)i * 8);
#pragma unroll
    for (int j = 0; j < 8; ++j) s[j] += bf2f(v[j]);
  }
  f32x4 o0, o1;
#pragma unroll
  for (int j = 0; j < 4; ++j) { o0[j] = s[j] * inv; o1[j] = s[4 + j] * inv; }
  f32x4* po = (f32x4*)(out + (size_t)i * 8);
  po[0] = o0; po[1] = o1;
}

// ---------- 256x256 bf16 GEMM, B^T convention, 8-phase counted-vmcnt schedule ----------
// 512 thr = 8 waves (2M x 4N), wave C = 128x64 = acc[8][4]. BK=64 as 2 ks-halves of 32.
// LDS: As/Bs[2 dbuf][2 ks][256 rows x 32 cols] = 128 KiB. Staging unit (half-tile) =
// one (matrix, ks) = 16KB = 2 gload_lds. Unit order per tile: B0,A0,B1,A1.
// Region last-read: B-ks0@p1, A-ks0@p2, B-ks1@p3, A-ks1@p4 (of its tile's 4 phases) ->
// stage stream p1: t+1*A1 | p2..p5: t+2*{B0,A0,B1,A1} | p6..p8: t+3*{B0,A0,B1}.
// vmcnt(6) at p4/p8 retires exactly the next tile's 8 loads (3 half-tiles stay in flight).
// Swizzle (both-sides, rule 21): granule p = q ^ ((row>>1)&3) on source AND read; linear
// LDS dest. 2 lanes/bank on ds_read_b128 = conflict-free.
// EPI: 0 = +bias -> bf16 (QKV, z = matrix)   1 = exp(s*scale)+rowsum -> bf16 (scores)
//      2 = split-K PV (z = K-slice, koff = z*K): bf16 partial stores
template <int EPI>
__global__ __launch_bounds__(512, 1) void gemm256(
    const unsigned short* __restrict__ A, const unsigned short* __restrict__ B,
    int lda, int ldb, int K, void* __restrict__ C, int ldc,
    size_t strideBz, size_t strideCz,
    const float* __restrict__ bq, const float* __restrict__ bk, const float* __restrict__ bv,
    float scale, float* __restrict__ rsum) {
  __shared__ unsigned short As[2][2][8192];  // [buf][ks][row*32+col], 256 rows
  __shared__ unsigned short Bs[2][2][8192];
  const int tid = threadIdx.x;
  const int lane = tid & 63;
  const int w = tid >> 6;
  const int wr = w >> 2;           // 0..1  M half
  const int wc = w & 3;            // 0..3  N quarter
  const int l16 = lane & 15;
  const int q = lane >> 4;         // 0..3
  const int swq = (q ^ ((l16 >> 1) & 3)) * 8;  // swizzled element offset within 32-col half

  // bijective XCD swizzle (nwg % 8 == 0 for all our grids)
  const int nwgx = gridDim.x;
  const int nwg = nwgx * gridDim.y;
  const int lin = blockIdx.y * nwgx + blockIdx.x;
  const int swz = (lin & 7) * (nwg >> 3) + (lin >> 3);
  const int m0 = (swz / nwgx) * 256;
  const int n0 = (swz % nwgx) * 256;
  const int z = blockIdx.z;
  const unsigned short* Bz = B + (size_t)z * strideBz;
  const size_t koff = (EPI == 2) ? (size_t)z * K : 0;

  f32x4 acc[8][4];
#pragma unroll
  for (int i = 0; i < 8; ++i)
#pragma unroll
    for (int j = 0; j < 4; ++j) acc[i][j] = f32x4{0.f, 0.f, 0.f, 0.f};

  // staging source pointers (source-side swizzle; LDS dest linear)
  const unsigned short* apA[2][2];
  const unsigned short* apB[2][2];
#pragma unroll
  for (int ks = 0; ks < 2; ++ks)
#pragma unroll
    for (int j = 0; j < 2; ++j) {
      const int g = (j << 9) + tid;
      const int row = g >> 2;
      const int sq = (g & 3) ^ ((row >> 1) & 3);
      apA[ks][j] = A + (size_t)(m0 + row) * lda + koff + ks * 32 + sq * 8;
      apB[ks][j] = Bz + (size_t)(n0 + row) * ldb + koff + ks * 32 + sq * 8;
    }

#define STG_A(BUF, KS, K0)                                      \
  do {                                                          \
    gload_lds16(apA[KS][0] + (K0), &As[BUF][KS][tid * 8]);      \
    gload_lds16(apA[KS][1] + (K0), &As[BUF][KS][(512 + tid) * 8]); \
  } while (0)
#define STG_B(BUF, KS, K0)                                      \
  do {                                                          \
    gload_lds16(apB[KS][0] + (K0), &Bs[BUF][KS][tid * 8]);      \
    gload_lds16(apB[KS][1] + (K0), &Bs[BUF][KS][(512 + tid) * 8]); \
  } while (0)

  short8 bfr[4], afr[4];
#define LDB4(KS, BUF)                                                         \
  do {                                                                        \
    _Pragma("unroll") for (int _n = 0; _n < 4; ++_n) {                        \
      const int _r = wc * 64 + _n * 16 + l16;                                 \
      bfr[_n] = *(const short8*)(&Bs[BUF][KS][_r * 32 + swq]);                \
    }                                                                         \
  } while (0)
#define LDA4(KS, MH, BUF)                                                     \
  do {                                                                        \
    _Pragma("unroll") for (int _m = 0; _m < 4; ++_m) {                        \
      const int _r = wr * 128 + ((MH) * 4 + _m) * 16 + l16;                   \
      afr[_m] = *(const short8*)(&As[BUF][KS][_r * 32 + swq]);                \
    }                                                                         \
  } while (0)
#define MMP(MH)                                                               \
  do {                                                                        \
    __builtin_amdgcn_s_setprio(1);                                            \
    _Pragma("unroll") for (int _m = 0; _m < 4; ++_m)                          \
      _Pragma("unroll") for (int _n = 0; _n < 4; ++_n)                        \
        acc[(MH) * 4 + _m][_n] = __builtin_amdgcn_mfma_f32_16x16x32_bf16(     \
            afr[_m], bfr[_n], acc[(MH) * 4 + _m][_n], 0, 0, 0);               \
    __builtin_amdgcn_s_setprio(0);                                            \
  } while (0)
#define PH_SYNC                                                               \
  do {                                                                        \
    __builtin_amdgcn_sched_barrier(0);                                        \
    __builtin_amdgcn_s_barrier();                                             \
    asm volatile("s_waitcnt lgkmcnt(0)" ::: "memory");                        \
    __builtin_amdgcn_sched_barrier(0);                                        \
  } while (0)
#define PH_END                                                                \
  do {                                                                        \
    __builtin_amdgcn_sched_barrier(0);                                        \
    __builtin_amdgcn_s_barrier();                                             \
    __builtin_amdgcn_sched_barrier(0);                                        \
  } while (0)

  const int NT = K / 64;  // NT even (>=2) for all our shapes
  // prologue: t0 complete (B0,A0,B1,A1) + t1 first 3 units (B0,A0,B1) = 14 loads
  STG_B(0, 0, 0); STG_A(0, 0, 0); STG_B(0, 1, 0); STG_A(0, 1, 0);
  if (1 < NT) { STG_B(1, 0, 64); STG_A(1, 0, 64); STG_B(1, 1, 64); }
  if (1 < NT) asm volatile("s_waitcnt vmcnt(6)" ::: "memory");  // t0 landed, 6 in flight
  else        asm volatile("s_waitcnt vmcnt(0)" ::: "memory");
  __builtin_amdgcn_s_barrier();

  for (int t = 0; t < NT; t += 2) {
    const bool more = (t + 2 < NT);  // for even NT: more  <=>  t+3 < NT
    const int k2 = (t + 2) * 64, k3 = (t + 3) * 64;
    // ---- tile t from buf0 ----
    // P1: ks0 mh0
    LDB4(0, 0); LDA4(0, 0, 0);
    STG_A(1, 1, (t + 1) * 64);                     // t+1 A-ks1 -> buf1 (read p8 prev iter)
    PH_SYNC; MMP(0); PH_END;
    // P2: ks0 mh1
    LDA4(0, 1, 0);
    if (more) STG_B(0, 0, k2);                     // buf0 B-ks0 freed at p1
    PH_SYNC; MMP(1); PH_END;
    // P3: ks1 mh0
    LDB4(1, 0); LDA4(1, 0, 0);
    if (more) STG_A(0, 0, k2);                     // buf0 A-ks0 freed at p2
    PH_SYNC; MMP(0); PH_END;
    // P4: ks1 mh1  + tile-boundary wait (t+1 must be fully landed)
    LDA4(1, 1, 0);
    if (more) STG_B(0, 1, k2);                     // buf0 B-ks1 freed at p3
    if (more) asm volatile("s_waitcnt vmcnt(6)" ::: "memory");
    else      asm volatile("s_waitcnt vmcnt(0)" ::: "memory");
    PH_SYNC; MMP(1); PH_END;
    // ---- tile t+1 from buf1 ----
    // P5: ks0 mh0
    LDB4(0, 1); LDA4(0, 0, 1);
    if (more) STG_A(0, 1, k2);                     // buf0 A-ks1 freed at p4
    PH_SYNC; MMP(0); PH_END;
    // P6: ks0 mh1
    LDA4(0, 1, 1);
    if (more) STG_B(1, 0, k3);                     // buf1 B-ks0 freed at p5
    PH_SYNC; MMP(1); PH_END;
    // P7: ks1 mh0
    LDB4(1, 1); LDA4(1, 0, 1);
    if (more) STG_A(1, 0, k3);                     // buf1 A-ks0 freed at p6
    PH_SYNC; MMP(0); PH_END;
    // P8: ks1 mh1 + tile-boundary wait (t+2 must be fully landed for next iter)
    LDA4(1, 1, 1);
    if (more) {
      STG_B(1, 1, k3);                             // buf1 B-ks1 freed at p7
      asm volatile("s_waitcnt vmcnt(6)" ::: "memory");
    }
    PH_SYNC; MMP(1); PH_END;
  }
#undef STG_A
#undef STG_B
#undef LDB4
#undef LDA4
#undef MMP
#undef PH_SYNC
#undef PH_END

  // epilogue: C/D layout col = l16, row = q*4 + r (per 16x16 fragment)
  const int row0 = m0 + wr * 128 + q * 4;
  const int col0 = n0 + wc * 64;

  if constexpr (EPI == 0) {
    unsigned short* O = (unsigned short*)C + (size_t)z * strideCz;
    const float* bias = (z == 0) ? bq : ((z == 1) ? bk : bv);
#pragma unroll
    for (int mi = 0; mi < 8; ++mi)
#pragma unroll
      for (int ni = 0; ni < 4; ++ni) {
        const int col = col0 + ni * 16 + l16;
        const int row = row0 + mi * 16;
        float bvv = bias[col];
#pragma unroll
        for (int r = 0; r < 4; ++r)
          O[(size_t)(row + r) * ldc + col] = f2bf(acc[mi][ni][r] + bvv);
      }
  } else if constexpr (EPI == 1) {
    // exp + fused row-sum of the bf16-ROUNDED values (exactly what PV consumes)
    unsigned short* O = (unsigned short*)C;
#pragma unroll
    for (int mi = 0; mi < 8; ++mi) {
      float rs[4] = {0.f, 0.f, 0.f, 0.f};
      const int row = row0 + mi * 16;
#pragma unroll
      for (int ni = 0; ni < 4; ++ni) {
        const int col = col0 + ni * 16 + l16;
#pragma unroll
        for (int r = 0; r < 4; ++r) {
          unsigned short ub = f2bf(__expf(acc[mi][ni][r] * scale));
          O[(size_t)(row + r) * ldc + col] = ub;
          rs[r] += bf2f(ub);
        }
      }
#pragma unroll
      for (int off = 1; off <= 8; off <<= 1) {
#pragma unroll
        for (int r = 0; r < 4; ++r) rs[r] += __shfl_xor(rs[r], off);
      }
      if (l16 == 0) {
#pragma unroll
        for (int r = 0; r < 4; ++r) unsafeAtomicAdd(&rsum[row + r], rs[r]);
      }
    }
  } else {
    // split-K PV: plain bf16 partial stores
    unsigned short* O = (unsigned short*)C + (size_t)z * strideCz;
#pragma unroll
    for (int mi = 0; mi < 8; ++mi)
#pragma unroll
      for (int ni = 0; ni < 4; ++ni) {
        const int col = col0 + ni * 16 + l16;
        const int row = row0 + mi * 16;
#pragma unroll
        for (int r = 0; r < 4; ++r)
          O[(size_t)(row + r) * ldc + col] = f2bf(acc[mi][ni][r]);
      }
  }
}

// ---------- launch ----------
extern "C" void kernel_launch(void* const* d_in, const int* in_sizes, int n_in,
                              void* d_out, int out_size, void* d_ws, size_t ws_size,
                              hipStream_t stream) {
  const float* x  = (const float*)d_in[0];
  const float* Wq = (const float*)d_in[1];
  const float* bq = (const float*)d_in[2];
  const float* Wk = (const float*)d_in[3];
  const float* bk = (const float*)d_in[4];
  const float* Wv = (const float*)d_in[5];
  const float* bv = (const float*)d_in[6];
  float* out = (float*)d_out;
  char* ws = (char*)d_ws;
  const size_t MB = 1024 * 1024;

  // ws layout (78 MB). Phase A: xb 0-8 | wt 8-14 | qkv 14-38 | vt 38-46 | S 46-78
  //                    Phase B (PV): P 0-32 (xb/wt/qb/kb/vb-head dead) | rsum@37 | vt | S
  unsigned short* xb  = (unsigned short*)(ws + 0);
  unsigned short* wt  = (unsigned short*)(ws + 8 * MB);
  unsigned short* qkv = (unsigned short*)(ws + 14 * MB);
  unsigned short* qb  = qkv;
  unsigned short* kb  = qkv + (size_t)4194304;
  unsigned short* vb  = qkv + (size_t)2 * 4194304;
  float*          rsum= (float*)(ws + 37 * MB);
  unsigned short* vt  = (unsigned short*)(ws + 38 * MB);
  unsigned short* S   = (unsigned short*)(ws + 46 * MB);
  unsigned short* P   = (unsigned short*)(ws + 0);

  // 1) convert x to bf16
  conv_f32_bf16<<<2048, 256, 0, stream>>>(x, xb, 524288);
  // 2) transpose+convert the three weight matrices
  transconv_w<<<dim3(16, 16, 3), 256, 0, stream>>>(Wq, Wk, Wv, wt);
  // 3) QKV projection (bias fused, bf16 out)
  gemm256<0><<<dim3(4, 16, 3), 512, 0, stream>>>(
      xb, wt, 1024, 1024, 1024, qkv, 1024,
      (size_t)1048576, (size_t)4194304, bq, bk, bv, 1.0f, nullptr);
  // 4) transpose v -> vt
  trans_bf16<<<dim3(64, 16), 256, 0, stream>>>(vb, vt, 4096, 1024);
  // 4b) zero rsum (vb dead; rsum lives in its tail)
  hipMemsetAsync(rsum, 0, 4096 * sizeof(float), stream);
  // 5) E = exp(q k^T / 32) with fused rsum accumulation
  gemm256<1><<<dim3(16, 16), 512, 0, stream>>>(
      qb, kb, 1024, 1024, 1024, S, 4096,
      (size_t)0, (size_t)0, nullptr, nullptr, nullptr, 0.03125f, rsum);
  // 6) PV split-K x4: P[z] = E[:, z*1024:+1024] @ v[z*1024:+1024, :]
  gemm256<2><<<dim3(4, 16, 4), 512, 0, stream>>>(
      S, vt, 4096, 4096, 1024, P, 1024,
      (size_t)0, (size_t)4194304, nullptr, nullptr, nullptr, 1.0f, nullptr);
  // 7) out = (sum_z P[z]) / rsum
  reduce_pv<<<2048, 256, 0, stream>>>(P, rsum, out);
}